// Round 1
// baseline (207.149 us; speedup 1.0000x reference)
//
#include <hip/hip_runtime.h>

#define E_TOTAL 600000
#define DFEAT   128
#define TILE    64
#define PK      136   // padded row stride in bf16 elements (128 + 8)

typedef __attribute__((ext_vector_type(8))) short  short8;
typedef __attribute__((ext_vector_type(4))) float  f32x4;

static __device__ __forceinline__ unsigned short f2bf(float f) {
    unsigned int u = __float_as_uint(f);
    unsigned int r = (u + 0x7fffu + ((u >> 16) & 1u)) >> 16;
    return (unsigned short)r;
}

// Cast + transpose weights into ws: W1 [256][128] f32 -> w1t [128][256] bf16,
// W2 [128][64] f32 -> w2t [64][128] bf16.
__global__ void prep_weights(const float* __restrict__ W1, const float* __restrict__ W2,
                             unsigned short* __restrict__ w1t, unsigned short* __restrict__ w2t) {
    int i = blockIdx.x * blockDim.x + threadIdx.x;
    if (i < 256 * 128) {
        int c = i >> 8;       // dest row (out-channel) 0..127
        int k = i & 255;      // dest col (in-channel)  0..255
        w1t[i] = f2bf(W1[k * 128 + c]);
    } else {
        int j = i - 256 * 128;
        if (j < 128 * 64) {
            int c = j >> 7;   // 0..63
            int k = j & 127;  // 0..127
            w2t[j] = f2bf(W2[k * 64 + c]);
        }
    }
}

__global__ __launch_bounds__(256) void edge_mlp_kernel(
        const float* __restrict__ enc,
        const int*   __restrict__ eidx,
        const float* __restrict__ b1,
        const float* __restrict__ b2,
        const float* __restrict__ W3,
        const float* __restrict__ b3,
        const unsigned short* __restrict__ w1t,
        const unsigned short* __restrict__ w2t,
        float* __restrict__ out)
{
    __shared__ unsigned short sW[128][PK];   // W1t chunk; later rows 0..63 = W2t, rows 64..127 = h2 (f32)
    __shared__ unsigned short sX[TILE][PK];  // X chunk; later h1 (bf16)
    __shared__ int   sIdx[2][TILE];
    __shared__ float sConst[324];            // [0,128) b1 | [128,192) b2 | [192,320) W3 | [320,322) b3

    const int tid  = threadIdx.x;
    const int lane = tid & 63;
    const int w    = tid >> 6;
    const int wm   = w >> 1;            // 0..1 -> row half
    const int wn   = w & 1;             // 0..1 -> col half
    const int e0   = blockIdx.x * TILE;

    // ---- stage edge indices + small constants ----
    if (tid < 64)       sIdx[0][tid]      = eidx[e0 + tid];              // row endpoint
    else if (tid < 128) sIdx[1][tid - 64] = eidx[E_TOTAL + e0 + tid - 64]; // col endpoint
    for (int j = tid; j < 322; j += 256) {
        float v;
        if (j < 128)      v = b1[j];
        else if (j < 192) v = b2[j - 128];
        else if (j < 320) v = W3[j - 192];
        else              v = b3[j - 320];
        sConst[j] = v;
    }
    __syncthreads();

    // ---- GEMM1: [64 x 256] @ [256 x 128], K split in two 128-chunks ----
    f32x4 acc[2][4];
#pragma unroll
    for (int mi = 0; mi < 2; ++mi)
#pragma unroll
        for (int ni = 0; ni < 4; ++ni)
            acc[mi][ni] = (f32x4){0.f, 0.f, 0.f, 0.f};

    const int acol = lane & 15;
    const int kgrp = (lane >> 4) * 8;

#pragma unroll
    for (int kc = 0; kc < 2; ++kc) {
        // load W1t chunk [128 cols][128 k] into sW
        {
            int c = tid >> 1, h = tid & 1;
            const unsigned short* src = w1t + c * 256 + kc * 128 + h * 64;
            unsigned short* dst = &sW[c][h * 64];
#pragma unroll
            for (int i = 0; i < 8; ++i)
                *reinterpret_cast<short8*>(dst + i * 8) =
                    *reinterpret_cast<const short8*>(src + i * 8);
        }
        // gather endpoint features -> bf16 into sX
        {
            int e = tid >> 2, p = tid & 3;
            int node = sIdx[kc][e];
            const float* src = enc + (long)node * DFEAT + p * 32;
#pragma unroll
            for (int i = 0; i < 4; ++i) {
                float4 v0 = *reinterpret_cast<const float4*>(src + i * 8);
                float4 v1 = *reinterpret_cast<const float4*>(src + i * 8 + 4);
                short8 pv;
                pv[0] = (short)f2bf(v0.x); pv[1] = (short)f2bf(v0.y);
                pv[2] = (short)f2bf(v0.z); pv[3] = (short)f2bf(v0.w);
                pv[4] = (short)f2bf(v1.x); pv[5] = (short)f2bf(v1.y);
                pv[6] = (short)f2bf(v1.z); pv[7] = (short)f2bf(v1.w);
                *reinterpret_cast<short8*>(&sX[e][p * 32 + i * 8]) = pv;
            }
        }
        __syncthreads();
#pragma unroll
        for (int kk = 0; kk < 4; ++kk) {
            int kb = kk * 32 + kgrp;
            short8 a[2], b[4];
#pragma unroll
            for (int mi = 0; mi < 2; ++mi)
                a[mi] = *reinterpret_cast<const short8*>(&sX[wm * 32 + mi * 16 + acol][kb]);
#pragma unroll
            for (int ni = 0; ni < 4; ++ni)
                b[ni] = *reinterpret_cast<const short8*>(&sW[wn * 64 + ni * 16 + acol][kb]);
#pragma unroll
            for (int mi = 0; mi < 2; ++mi)
#pragma unroll
                for (int ni = 0; ni < 4; ++ni)
                    acc[mi][ni] = __builtin_amdgcn_mfma_f32_16x16x32_bf16(
                        a[mi], b[ni], acc[mi][ni], 0, 0, 0);
        }
        __syncthreads();
    }

    // ---- epilogue1: h1 = relu(acc + b1) -> bf16 into sX; load W2t into sW[0..63] ----
#pragma unroll
    for (int mi = 0; mi < 2; ++mi) {
        int row0 = wm * 32 + mi * 16 + ((lane >> 4) << 2);
#pragma unroll
        for (int ni = 0; ni < 4; ++ni) {
            int col = wn * 64 + ni * 16 + acol;
            float bias = sConst[col];
#pragma unroll
            for (int r = 0; r < 4; ++r) {
                float v = acc[mi][ni][r] + bias;
                v = v > 0.f ? v : 0.f;
                sX[row0 + r][col] = f2bf(v);
            }
        }
    }
    {
        int c = tid >> 2, q = tid & 3;
        const unsigned short* src = w2t + c * 128 + q * 32;
        unsigned short* dst = &sW[c][q * 32];
#pragma unroll
        for (int i = 0; i < 4; ++i)
            *reinterpret_cast<short8*>(dst + i * 8) =
                *reinterpret_cast<const short8*>(src + i * 8);
    }
    __syncthreads();

    // ---- GEMM2: [64 x 128] @ [128 x 64] ----
    f32x4 acc2[2][2];
#pragma unroll
    for (int mi = 0; mi < 2; ++mi)
#pragma unroll
        for (int ni = 0; ni < 2; ++ni)
            acc2[mi][ni] = (f32x4){0.f, 0.f, 0.f, 0.f};

#pragma unroll
    for (int kk = 0; kk < 4; ++kk) {
        int kb = kk * 32 + kgrp;
        short8 a2[2], bb[2];
#pragma unroll
        for (int mi = 0; mi < 2; ++mi)
            a2[mi] = *reinterpret_cast<const short8*>(&sX[wm * 32 + mi * 16 + acol][kb]);
#pragma unroll
        for (int ni = 0; ni < 2; ++ni)
            bb[ni] = *reinterpret_cast<const short8*>(&sW[wn * 32 + ni * 16 + acol][kb]);
#pragma unroll
        for (int mi = 0; mi < 2; ++mi)
#pragma unroll
            for (int ni = 0; ni < 2; ++ni)
                acc2[mi][ni] = __builtin_amdgcn_mfma_f32_16x16x32_bf16(
                    a2[mi], bb[ni], acc2[mi][ni], 0, 0, 0);
    }

    // ---- epilogue2: h2 = relu(acc2 + b2) -> f32 into sH2 (= sW rows 64..127) ----
    float* sH2 = reinterpret_cast<float*>(&sW[64][0]);   // [64][68] f32
#pragma unroll
    for (int mi = 0; mi < 2; ++mi) {
        int row0 = wm * 32 + mi * 16 + ((lane >> 4) << 2);
#pragma unroll
        for (int ni = 0; ni < 2; ++ni) {
            int col = wn * 32 + ni * 16 + acol;
            float bias = sConst[128 + col];
#pragma unroll
            for (int r = 0; r < 4; ++r) {
                float v = acc2[mi][ni][r] + bias;
                v = v > 0.f ? v : 0.f;
                sH2[(row0 + r) * 68 + col] = v;
            }
        }
    }
    __syncthreads();

    // ---- layer3 (N=2) + log_softmax on VALU ----
    if (tid < 128) {
        int e = tid >> 1, c = tid & 1;
        const float* h2row = sH2 + e * 68;
        float sum = sConst[320 + c];
#pragma unroll
        for (int k = 0; k < 64; ++k)
            sum = fmaf(h2row[k], sConst[192 + k * 2 + c], sum);
        float other = __shfl_xor(sum, 1, 64);
        float m   = fmaxf(sum, other);
        float lse = m + logf(expf(sum - m) + expf(other - m));
        out[e0 * 2 + tid] = sum - lse;
    }
}

extern "C" void kernel_launch(void* const* d_in, const int* in_sizes, int n_in,
                              void* d_out, int out_size, void* d_ws, size_t ws_size,
                              hipStream_t stream) {
    const float* enc = (const float*)d_in[0];
    const int*   eidx = (const int*)d_in[1];
    const float* W1 = (const float*)d_in[2];
    const float* b1 = (const float*)d_in[3];
    const float* W2 = (const float*)d_in[4];
    const float* b2 = (const float*)d_in[5];
    const float* W3 = (const float*)d_in[6];
    const float* b3 = (const float*)d_in[7];
    float* out = (float*)d_out;

    unsigned short* w1t = (unsigned short*)d_ws;          // 128*256 bf16 = 64 KB
    unsigned short* w2t = w1t + 256 * 128;                // 64*128 bf16 = 16 KB

    prep_weights<<<(256 * 128 + 128 * 64 + 255) / 256, 256, 0, stream>>>(W1, W2, w1t, w2t);
    edge_mlp_kernel<<<E_TOTAL / TILE, 256, 0, stream>>>(enc, eidx, b1, b2, W3, b3,
                                                        w1t, w2t, out);
}

// Round 2
// 116.680 us; speedup vs baseline: 1.7754x; 1.7754x over previous
//
#include <hip/hip_runtime.h>

#define E_TOTAL  600000
#define N_NODES  100000
#define DFEAT    128
#define NTILES   4688          // ceil(E_TOTAL / 128)
#define TPB_TILES 2
#define GRID_MAIN 2344         // NTILES / TPB_TILES

typedef __attribute__((ext_vector_type(8))) short  short8;
typedef __attribute__((ext_vector_type(4))) float  f32x4;

static __device__ __forceinline__ unsigned short f2bf(float f) {
    unsigned int u = __float_as_uint(f);
    unsigned int r = (u + 0x7fffu + ((u >> 16) & 1u)) >> 16;
    return (unsigned short)r;
}
static __device__ __forceinline__ float bf2f(unsigned short u) {
    unsigned int x = ((unsigned int)u) << 16;
    return __uint_as_float(x);
}

// ============================ FAST PATH ============================

// w1abt[c][k], c in [0,256): c<128 -> W1[k][c] (src half); c>=128 -> W1[128+k][c-128] (dst half)
// w2t[c][k] = W2[k][c]
__global__ void prep_w_fast(const float* __restrict__ W1, const float* __restrict__ W2,
                            unsigned short* __restrict__ w1abt, unsigned short* __restrict__ w2t) {
    int i = blockIdx.x * blockDim.x + threadIdx.x;
    if (i < 256 * 128) {
        int c = i >> 7, k = i & 127;
        w1abt[i] = f2bf(W1[(k + (c & 128)) * 128 + (c & 127)]);
    } else {
        int j = i - 256 * 128;
        if (j < 64 * 128) {
            int c = j >> 7, k = j & 127;
            w2t[j] = f2bf(W2[k * 64 + c]);
        }
    }
}

// PQ[n][0:128] = enc[n] @ W1a + b1 ; PQ[n][128:256] = enc[n] @ W1b   (bf16)
__global__ __launch_bounds__(256, 2) void build_pq(
        const float* __restrict__ enc, const float* __restrict__ b1,
        const unsigned short* __restrict__ w1abt, unsigned short* __restrict__ PQ)
{
    __shared__ unsigned short sX[64 * 128];     // swizzled bf16 enc tile
    __shared__ unsigned short sOut[64 * 264];   // padded bounce for coalesced writeout

    const int tid = threadIdx.x, lane = tid & 63, w = tid >> 6;
    const int acol = lane & 15, g = lane >> 4;
    const int n0 = blockIdx.x * 64;

    // stage enc tile -> bf16, XOR-swizzled
    {
        int r = tid >> 2, q = tid & 3;
        int n = n0 + r; if (n >= N_NODES) n = N_NODES - 1;
        const float* src = enc + (size_t)n * DFEAT + q * 32;
#pragma unroll
        for (int i = 0; i < 4; ++i) {
            float4 v0 = *reinterpret_cast<const float4*>(src + i * 8);
            float4 v1 = *reinterpret_cast<const float4*>(src + i * 8 + 4);
            short8 pv;
            pv[0] = (short)f2bf(v0.x); pv[1] = (short)f2bf(v0.y);
            pv[2] = (short)f2bf(v0.z); pv[3] = (short)f2bf(v0.w);
            pv[4] = (short)f2bf(v1.x); pv[5] = (short)f2bf(v1.y);
            pv[6] = (short)f2bf(v1.z); pv[7] = (short)f2bf(v1.w);
            int chunk = (q * 4 + i) ^ (r & 7);
            *reinterpret_cast<short8*>(&sX[r * 128 + chunk * 8]) = pv;
        }
    }

    // B-fragments direct from global (L2-hot), + b1
    short8 bf[4][4];
#pragma unroll
    for (int ks = 0; ks < 4; ++ks)
#pragma unroll
        for (int ni = 0; ni < 4; ++ni) {
            int c = w * 64 + ni * 16 + acol;
            bf[ks][ni] = *reinterpret_cast<const short8*>(w1abt + c * 128 + ks * 32 + g * 8);
        }
    float b1v[4];
#pragma unroll
    for (int ni = 0; ni < 4; ++ni) {
        int c = w * 64 + ni * 16 + acol;
        b1v[ni] = (c < 128) ? b1[c] : 0.f;
    }
    __syncthreads();

    f32x4 acc[4][4];
#pragma unroll
    for (int mi = 0; mi < 4; ++mi)
#pragma unroll
        for (int ni = 0; ni < 4; ++ni)
            acc[mi][ni] = (f32x4){0.f, 0.f, 0.f, 0.f};

#pragma unroll
    for (int ks = 0; ks < 4; ++ks) {
        short8 a[4];
#pragma unroll
        for (int mi = 0; mi < 4; ++mi) {
            int r = mi * 16 + acol;
            a[mi] = *reinterpret_cast<const short8*>(&sX[r * 128 + (((ks * 4 + g) ^ (r & 7)) * 8)]);
        }
#pragma unroll
        for (int mi = 0; mi < 4; ++mi)
#pragma unroll
            for (int ni = 0; ni < 4; ++ni)
                acc[mi][ni] = __builtin_amdgcn_mfma_f32_16x16x32_bf16(a[mi], bf[ks][ni], acc[mi][ni], 0, 0, 0);
    }

    // epilogue -> padded LDS, then coalesced global writeout
#pragma unroll
    for (int mi = 0; mi < 4; ++mi)
#pragma unroll
        for (int ni = 0; ni < 4; ++ni)
#pragma unroll
            for (int rr = 0; rr < 4; ++rr) {
                int row = mi * 16 + g * 4 + rr;
                int col = w * 64 + ni * 16 + acol;
                sOut[row * 264 + col] = f2bf(acc[mi][ni][rr] + b1v[ni]);
            }
    __syncthreads();
    {
        int r = tid >> 2, q = tid & 3;
        int n = n0 + r;
        if (n < N_NODES) {
            unsigned short* dst = PQ + (size_t)n * 256 + q * 64;
#pragma unroll
            for (int i = 0; i < 8; ++i)
                *reinterpret_cast<short8*>(dst + i * 8) =
                    *reinterpret_cast<const short8*>(&sOut[r * 264 + q * 64 + i * 8]);
        }
    }
}

// per-edge head: h1 = relu(P[src]+Q[dst]); h2 = relu(h1@W2+b2); logsoftmax(h2@W3+b3)
__global__ __launch_bounds__(512, 4) void edge_head(
        const unsigned short* __restrict__ PQ,
        const int* __restrict__ eidx,
        const unsigned short* __restrict__ w2t,
        const float* __restrict__ b2, const float* __restrict__ W3, const float* __restrict__ b3,
        float* __restrict__ out)
{
    __shared__ unsigned short sH1[128 * 128];   // swizzled bf16 h1 tile
    __shared__ unsigned short sW2[64 * 136];    // padded W2^T
    __shared__ float part[2][128][2];

    const int tid = threadIdx.x, lane = tid & 63, w = tid >> 6;
    const int acol = lane & 15, g = lane >> 4;
    const int wm = w >> 1, wn = w & 1;
    const int le = tid >> 2, q = tid & 3;

    // stage W2^T once per block
    {
        int c = tid >> 3, s = tid & 7;
        *reinterpret_cast<short8*>(&sW2[c * 136 + s * 16]) =
            *reinterpret_cast<const short8*>(w2t + c * 128 + s * 16);
        *reinterpret_cast<short8*>(&sW2[c * 136 + s * 16 + 8]) =
            *reinterpret_cast<const short8*>(w2t + c * 128 + s * 16 + 8);
    }
    float b2v[2], w3v[2][2];
#pragma unroll
    for (int ni = 0; ni < 2; ++ni) {
        int c = wn * 32 + ni * 16 + acol;
        b2v[ni] = b2[c];
        w3v[ni][0] = W3[c * 2]; w3v[ni][1] = W3[c * 2 + 1];
    }

    const int tile0 = blockIdx.x * TPB_TILES;
    short8 rp[4], rq[4];
    {   // prologue gather for first tile
        int e = tile0 * 128 + le; if (e >= E_TOTAL) e = E_TOTAL - 1;
        int s = eidx[e], d2 = eidx[E_TOTAL + e];
        const unsigned short* ps = PQ + (size_t)s * 256 + q * 32;
        const unsigned short* pd = PQ + (size_t)d2 * 256 + 128 + q * 32;
#pragma unroll
        for (int i = 0; i < 4; ++i) {
            rp[i] = *reinterpret_cast<const short8*>(ps + i * 8);
            rq[i] = *reinterpret_cast<const short8*>(pd + i * 8);
        }
    }
    __syncthreads();   // sW2 ready

    for (int tl = 0; tl < TPB_TILES; ++tl) {
        const int tile = tile0 + tl;

        // h1 = relu(P+Q) -> bf16 swizzled into sH1
#pragma unroll
        for (int i = 0; i < 4; ++i) {
            short8 hv;
#pragma unroll
            for (int j = 0; j < 8; ++j) {
                float v = bf2f((unsigned short)rp[i][j]) + bf2f((unsigned short)rq[i][j]);
                v = v > 0.f ? v : 0.f;
                hv[j] = (short)f2bf(v);
            }
            int chunk = (q * 4 + i) ^ (le & 7);
            *reinterpret_cast<short8*>(&sH1[le * 128 + chunk * 8]) = hv;
        }

        // prefetch next tile's gather (hidden under GEMM2 + layer3)
        if (tl + 1 < TPB_TILES) {
            int e = (tile + 1) * 128 + le; if (e >= E_TOTAL) e = E_TOTAL - 1;
            int s = eidx[e], d2 = eidx[E_TOTAL + e];
            const unsigned short* ps = PQ + (size_t)s * 256 + q * 32;
            const unsigned short* pd = PQ + (size_t)d2 * 256 + 128 + q * 32;
#pragma unroll
            for (int i = 0; i < 4; ++i) {
                rp[i] = *reinterpret_cast<const short8*>(ps + i * 8);
                rq[i] = *reinterpret_cast<const short8*>(pd + i * 8);
            }
        }
        __syncthreads();   // barrier 1: sH1 ready

        // GEMM2: [128 x 128] @ [128 x 64]
        f32x4 acc2[2][2];
#pragma unroll
        for (int mi = 0; mi < 2; ++mi)
#pragma unroll
            for (int ni = 0; ni < 2; ++ni)
                acc2[mi][ni] = (f32x4){0.f, 0.f, 0.f, 0.f};
#pragma unroll
        for (int ks = 0; ks < 4; ++ks) {
            short8 a2[2], bb[2];
#pragma unroll
            for (int mi = 0; mi < 2; ++mi) {
                int r = wm * 32 + mi * 16 + acol;
                a2[mi] = *reinterpret_cast<const short8*>(&sH1[r * 128 + (((ks * 4 + g) ^ (r & 7)) * 8)]);
            }
#pragma unroll
            for (int ni = 0; ni < 2; ++ni) {
                int c = wn * 32 + ni * 16 + acol;
                bb[ni] = *reinterpret_cast<const short8*>(&sW2[c * 136 + ks * 32 + g * 8]);
            }
#pragma unroll
            for (int mi = 0; mi < 2; ++mi)
#pragma unroll
                for (int ni = 0; ni < 2; ++ni)
                    acc2[mi][ni] = __builtin_amdgcn_mfma_f32_16x16x32_bf16(a2[mi], bb[ni], acc2[mi][ni], 0, 0, 0);
        }

        // layer3 partial logits in registers
        float p[8][2];
#pragma unroll
        for (int k = 0; k < 8; ++k) { p[k][0] = 0.f; p[k][1] = 0.f; }
#pragma unroll
        for (int mi = 0; mi < 2; ++mi)
#pragma unroll
            for (int ni = 0; ni < 2; ++ni)
#pragma unroll
                for (int rr = 0; rr < 4; ++rr) {
                    float h = acc2[mi][ni][rr] + b2v[ni];
                    h = h > 0.f ? h : 0.f;
                    p[mi * 4 + rr][0] = fmaf(h, w3v[ni][0], p[mi * 4 + rr][0]);
                    p[mi * 4 + rr][1] = fmaf(h, w3v[ni][1], p[mi * 4 + rr][1]);
                }
        // reduce over the 16 acol lanes (butterfly stays within each 16-lane group)
#pragma unroll
        for (int d = 1; d < 16; d <<= 1)
#pragma unroll
            for (int k = 0; k < 8; ++k) {
                p[k][0] += __shfl_xor(p[k][0], d, 64);
                p[k][1] += __shfl_xor(p[k][1], d, 64);
            }
        if (acol < 2) {
#pragma unroll
            for (int mi = 0; mi < 2; ++mi)
#pragma unroll
                for (int rr = 0; rr < 4; ++rr) {
                    int row = wm * 32 + mi * 16 + g * 4 + rr;
                    part[wn][row][acol] = p[mi * 4 + rr][acol];
                }
        }
        __syncthreads();   // barrier 2: part ready, sH1 free

        if (tid < 256) {
            int e = tid >> 1, c = tid & 1;
            float v = part[0][e][c] + part[1][e][c] + b3[c];
            float o = __shfl_xor(v, 1, 64);
            float m = fmaxf(v, o);
            float lse = m + logf(expf(v - m) + expf(o - m));
            int ge = tile * 128 + e;
            if (ge < E_TOTAL) out[(size_t)ge * 2 + c] = v - lse;
        }
    }
}

// ============================ FALLBACK PATH (round-1, proven) ============================

#define TILE    64
#define PK      136

__global__ void prep_weights(const float* __restrict__ W1, const float* __restrict__ W2,
                             unsigned short* __restrict__ w1t, unsigned short* __restrict__ w2t) {
    int i = blockIdx.x * blockDim.x + threadIdx.x;
    if (i < 256 * 128) {
        int c = i >> 8;
        int k = i & 255;
        w1t[i] = f2bf(W1[k * 128 + c]);
    } else {
        int j = i - 256 * 128;
        if (j < 128 * 64) {
            int c = j >> 7;
            int k = j & 127;
            w2t[j] = f2bf(W2[k * 64 + c]);
        }
    }
}

__global__ __launch_bounds__(256) void edge_mlp_kernel(
        const float* __restrict__ enc,
        const int*   __restrict__ eidx,
        const float* __restrict__ b1,
        const float* __restrict__ b2,
        const float* __restrict__ W3,
        const float* __restrict__ b3,
        const unsigned short* __restrict__ w1t,
        const unsigned short* __restrict__ w2t,
        float* __restrict__ out)
{
    __shared__ unsigned short sW[128][PK];
    __shared__ unsigned short sX[TILE][PK];
    __shared__ int   sIdx[2][TILE];
    __shared__ float sConst[324];

    const int tid  = threadIdx.x;
    const int lane = tid & 63;
    const int w    = tid >> 6;
    const int wm   = w >> 1;
    const int wn   = w & 1;
    const int e0   = blockIdx.x * TILE;

    if (tid < 64)       sIdx[0][tid]      = eidx[e0 + tid];
    else if (tid < 128) sIdx[1][tid - 64] = eidx[E_TOTAL + e0 + tid - 64];
    for (int j = tid; j < 322; j += 256) {
        float v;
        if (j < 128)      v = b1[j];
        else if (j < 192) v = b2[j - 128];
        else if (j < 320) v = W3[j - 192];
        else              v = b3[j - 320];
        sConst[j] = v;
    }
    __syncthreads();

    f32x4 acc[2][4];
#pragma unroll
    for (int mi = 0; mi < 2; ++mi)
#pragma unroll
        for (int ni = 0; ni < 4; ++ni)
            acc[mi][ni] = (f32x4){0.f, 0.f, 0.f, 0.f};

    const int acol = lane & 15;
    const int kgrp = (lane >> 4) * 8;

#pragma unroll
    for (int kc = 0; kc < 2; ++kc) {
        {
            int c = tid >> 1, h = tid & 1;
            const unsigned short* src = w1t + c * 256 + kc * 128 + h * 64;
            unsigned short* dst = &sW[c][h * 64];
#pragma unroll
            for (int i = 0; i < 8; ++i)
                *reinterpret_cast<short8*>(dst + i * 8) =
                    *reinterpret_cast<const short8*>(src + i * 8);
        }
        {
            int e = tid >> 2, p = tid & 3;
            int node = sIdx[kc][e];
            const float* src = enc + (long)node * DFEAT + p * 32;
#pragma unroll
            for (int i = 0; i < 4; ++i) {
                float4 v0 = *reinterpret_cast<const float4*>(src + i * 8);
                float4 v1 = *reinterpret_cast<const float4*>(src + i * 8 + 4);
                short8 pv;
                pv[0] = (short)f2bf(v0.x); pv[1] = (short)f2bf(v0.y);
                pv[2] = (short)f2bf(v0.z); pv[3] = (short)f2bf(v0.w);
                pv[4] = (short)f2bf(v1.x); pv[5] = (short)f2bf(v1.y);
                pv[6] = (short)f2bf(v1.z); pv[7] = (short)f2bf(v1.w);
                *reinterpret_cast<short8*>(&sX[e][p * 32 + i * 8]) = pv;
            }
        }
        __syncthreads();
#pragma unroll
        for (int kk = 0; kk < 4; ++kk) {
            int kb = kk * 32 + kgrp;
            short8 a[2], b[4];
#pragma unroll
            for (int mi = 0; mi < 2; ++mi)
                a[mi] = *reinterpret_cast<const short8*>(&sX[wm * 32 + mi * 16 + acol][kb]);
#pragma unroll
            for (int ni = 0; ni < 4; ++ni)
                b[ni] = *reinterpret_cast<const short8*>(&sW[wn * 64 + ni * 16 + acol][kb]);
#pragma unroll
            for (int mi = 0; mi < 2; ++mi)
#pragma unroll
                for (int ni = 0; ni < 4; ++ni)
                    acc[mi][ni] = __builtin_amdgcn_mfma_f32_16x16x32_bf16(
                        a[mi], b[ni], acc[mi][ni], 0, 0, 0);
        }
        __syncthreads();
    }

#pragma unroll
    for (int mi = 0; mi < 2; ++mi) {
        int row0 = wm * 32 + mi * 16 + ((lane >> 4) << 2);
#pragma unroll
        for (int ni = 0; ni < 4; ++ni) {
            int col = wn * 64 + ni * 16 + acol;
            float bias = sConst[col];
#pragma unroll
            for (int r = 0; r < 4; ++r) {
                float v = acc[mi][ni][r] + bias;
                v = v > 0.f ? v : 0.f;
                sX[row0 + r][col] = f2bf(v);
            }
        }
    }
    {
        int c = tid >> 2, q = tid & 3;
        const unsigned short* src = w2t + c * 128 + q * 32;
        unsigned short* dst = &sW[c][q * 32];
#pragma unroll
        for (int i = 0; i < 4; ++i)
            *reinterpret_cast<short8*>(dst + i * 8) =
                *reinterpret_cast<const short8*>(src + i * 8);
    }
    __syncthreads();

    f32x4 acc2[2][2];
#pragma unroll
    for (int mi = 0; mi < 2; ++mi)
#pragma unroll
        for (int ni = 0; ni < 2; ++ni)
            acc2[mi][ni] = (f32x4){0.f, 0.f, 0.f, 0.f};

#pragma unroll
    for (int kk = 0; kk < 4; ++kk) {
        int kb = kk * 32 + kgrp;
        short8 a2[2], bb[2];
#pragma unroll
        for (int mi = 0; mi < 2; ++mi)
            a2[mi] = *reinterpret_cast<const short8*>(&sX[wm * 32 + mi * 16 + acol][kb]);
#pragma unroll
        for (int ni = 0; ni < 2; ++ni)
            bb[ni] = *reinterpret_cast<const short8*>(&sW[wn * 32 + ni * 16 + acol][kb]);
#pragma unroll
        for (int mi = 0; mi < 2; ++mi)
#pragma unroll
            for (int ni = 0; ni < 2; ++ni)
                acc2[mi][ni] = __builtin_amdgcn_mfma_f32_16x16x32_bf16(
                    a2[mi], bb[ni], acc2[mi][ni], 0, 0, 0);
    }

    float* sH2 = reinterpret_cast<float*>(&sW[64][0]);
#pragma unroll
    for (int mi = 0; mi < 2; ++mi) {
        int row0 = wm * 32 + mi * 16 + ((lane >> 4) << 2);
#pragma unroll
        for (int ni = 0; ni < 2; ++ni) {
            int col = wn * 32 + ni * 16 + acol;
            float bias = sConst[128 + col];
#pragma unroll
            for (int r = 0; r < 4; ++r) {
                float v = acc2[mi][ni][r] + bias;
                v = v > 0.f ? v : 0.f;
                sH2[(row0 + r) * 68 + col] = v;
            }
        }
    }
    __syncthreads();

    if (tid < 128) {
        int e = tid >> 1, c = tid & 1;
        const float* h2row = sH2 + e * 68;
        float sum = sConst[320 + c];
#pragma unroll
        for (int k = 0; k < 64; ++k)
            sum = fmaf(h2row[k], sConst[192 + k * 2 + c], sum);
        float other = __shfl_xor(sum, 1, 64);
        float m   = fmaxf(sum, other);
        float lse = m + logf(expf(sum - m) + expf(other - m));
        out[e0 * 2 + tid] = sum - lse;
    }
}

// ============================ HOST ============================

extern "C" void kernel_launch(void* const* d_in, const int* in_sizes, int n_in,
                              void* d_out, int out_size, void* d_ws, size_t ws_size,
                              hipStream_t stream) {
    const float* enc = (const float*)d_in[0];
    const int*   eidx = (const int*)d_in[1];
    const float* W1 = (const float*)d_in[2];
    const float* b1 = (const float*)d_in[3];
    const float* W2 = (const float*)d_in[4];
    const float* b2 = (const float*)d_in[5];
    const float* W3 = (const float*)d_in[6];
    const float* b3 = (const float*)d_in[7];
    float* out = (float*)d_out;

    size_t needPQ = (size_t)N_NODES * 256 * 2;                       // 51.2 MB
    size_t need   = needPQ + 256 * 128 * 2 + 64 * 128 * 2;           // + 81.9 KB

    if (ws_size >= need) {
        unsigned short* PQ    = (unsigned short*)d_ws;
        unsigned short* w1abt = PQ + (size_t)N_NODES * 256;
        unsigned short* w2t   = w1abt + 256 * 128;
        prep_w_fast<<<160, 256, 0, stream>>>(W1, W2, w1abt, w2t);
        build_pq<<<(N_NODES + 63) / 64, 256, 0, stream>>>(enc, b1, w1abt, PQ);
        edge_head<<<GRID_MAIN, 512, 0, stream>>>(PQ, eidx, w2t, b2, W3, b3, out);
    } else {
        unsigned short* w1t = (unsigned short*)d_ws;
        unsigned short* w2t = w1t + 256 * 128;
        prep_weights<<<(256 * 128 + 128 * 64 + 255) / 256, 256, 0, stream>>>(W1, W2, w1t, w2t);
        edge_mlp_kernel<<<E_TOTAL / TILE, 256, 0, stream>>>(enc, eidx, b1, b2, W3, b3,
                                                            w1t, w2t, out);
    }
}